// Round 5
// baseline (103.226 us; speedup 1.0000x reference)
//
#include <hip/hip_runtime.h>
#include <math.h>

#define HIDDEN 128
#define NGRAPH 16384
#define SEG_BLOCKS 2048            // 8192 waves, ~62 rows each
#define MLP_ROWS 32
#define MLP_BLOCKS (NGRAPH / MLP_ROWS)   // 512

// shifted-softplus shift = log(2)
__device__ __constant__ float kSHIFT = 0.69314718055994530942f;

// ---------------------------------------------------------------------------
// Kernel 0: boundary scan -> offs[], plus zero u (stream-ordered before the
// atomic kernel). offs[g] = first row of graph g; offs[NGRAPH] = n_nodes.
// ---------------------------------------------------------------------------
__global__ __launch_bounds__(256) void offsets_kernel(
    const int* __restrict__ batch, int* __restrict__ offs,
    float4* __restrict__ u4, int n_nodes)
{
    const int i = blockIdx.x * blockDim.x + threadIdx.x;
    const int nthr = gridDim.x * blockDim.x;
    for (int j = i; j < NGRAPH * HIDDEN / 4; j += nthr)
        u4[j] = make_float4(0.f, 0.f, 0.f, 0.f);
    if (i >= n_nodes) return;
    int b = batch[i];
    int prev = (i == 0) ? -1 : batch[i - 1];
    for (int g = prev + 1; g <= b; ++g) offs[g] = i;        // rare
    if (i == n_nodes - 1)
        for (int g = b + 1; g <= NGRAPH; ++g) offs[g] = n_nodes;
}

// ---------------------------------------------------------------------------
// Kernel 1: chunked segment-sum. Each wave owns a contiguous row range of v
// (perfectly coalesced float4 streaming, 4 loads in flight per lane, no LDS,
// <=64 VGPR -> 8 waves/SIMD). Within the chunk it walks segments using offs
// for loop bounds (no per-row compares), accumulates the run in registers,
// and flushes once per segment with atomicAdd (low contention: each u address
// is touched by at most a couple of waves).
// Lane layout: f4 = l&31 owns one float4 column; ro = l>>5 is the row parity.
// ---------------------------------------------------------------------------
__global__ __launch_bounds__(256, 8) void seg_sum_kernel(
    const float* __restrict__ v, const int* __restrict__ batch,
    const int* __restrict__ offs, float* __restrict__ u,
    int n_nodes, int rows_per_wave)
{
    const int t   = threadIdx.x;
    const int wid = blockIdx.x * 4 + (t >> 6);
    const int l   = t & 63;
    const int f4  = l & 31;
    const int ro  = l >> 5;

    int r = wid * rows_per_wave;
    const int rend = min(r + rows_per_wave, n_nodes);
    const float4* __restrict__ v4 = reinterpret_cast<const float4*>(v);

    while (r < rend) {
        const int seg  = batch[r];            // wave-uniform (scalar path)
        const int stop = min(offs[seg + 1], rend);

        float4 a0 = make_float4(0.f, 0.f, 0.f, 0.f);
        float4 a1 = a0, a2 = a0, a3 = a0;
        int rr = r + ro;
        for (; rr + 6 < stop; rr += 8) {
            float4 x0 = v4[(size_t)rr      * 32 + f4];
            float4 x1 = v4[(size_t)(rr + 2) * 32 + f4];
            float4 x2 = v4[(size_t)(rr + 4) * 32 + f4];
            float4 x3 = v4[(size_t)(rr + 6) * 32 + f4];
            a0.x += x0.x; a0.y += x0.y; a0.z += x0.z; a0.w += x0.w;
            a1.x += x1.x; a1.y += x1.y; a1.z += x1.z; a1.w += x1.w;
            a2.x += x2.x; a2.y += x2.y; a2.z += x2.z; a2.w += x2.w;
            a3.x += x3.x; a3.y += x3.y; a3.z += x3.z; a3.w += x3.w;
        }
        for (; rr < stop; rr += 2) {
            float4 x = v4[(size_t)rr * 32 + f4];
            a0.x += x.x; a0.y += x.y; a0.z += x.z; a0.w += x.w;
        }
        float4 s;
        s.x = (a0.x + a1.x) + (a2.x + a3.x);
        s.y = (a0.y + a1.y) + (a2.y + a3.y);
        s.z = (a0.z + a1.z) + (a2.z + a3.z);
        s.w = (a0.w + a1.w) + (a2.w + a3.w);
        s.x += __shfl_xor(s.x, 32);
        s.y += __shfl_xor(s.y, 32);
        s.z += __shfl_xor(s.z, 32);
        s.w += __shfl_xor(s.w, 32);
        if (ro == 0) {
            float* dst = u + (size_t)seg * HIDDEN + f4 * 4;
            atomicAdd(dst + 0, s.x);
            atomicAdd(dst + 1, s.y);
            atomicAdd(dst + 2, s.z);
            atomicAdd(dst + 3, s.w);
        }
        r = stop;
    }
}

// ---------------------------------------------------------------------------
// Kernel 2: MLP. 512 blocks x 256 threads, 32 rows/block, acc[4][8] register
// blocking, W1 staged in 32-k-row chunks (32 KB) + u tile (16 KB) in LDS.
// u reads are L2/L3-hot (just produced). Epilogue: bias -> shifted softplus
// -> W2 contraction -> 32-lane shuffle reduce.
// ---------------------------------------------------------------------------
__global__ __launch_bounds__(256) void mlp_kernel(
    const float* __restrict__ u, const float* __restrict__ W1,
    const float* __restrict__ b1, const float* __restrict__ W2,
    const float* __restrict__ b2, float* __restrict__ out)
{
    __shared__ float u_s[MLP_ROWS * 128];   // 16 KB
    __shared__ float w_s[32 * 256];         // 32 KB

    const int t = threadIdx.x;
    const int row0 = blockIdx.x * MLP_ROWS;
    const int cg = t & 31;   // cols cg + 32j
    const int rg = t >> 5;   // rows rg + 8i

    const float4* __restrict__ u4g =
        reinterpret_cast<const float4*>(u + (size_t)row0 * 128);
    float4* u_s4 = reinterpret_cast<float4*>(u_s);
    #pragma unroll
    for (int q = 0; q < 4; ++q) u_s4[t + 256 * q] = u4g[t + 256 * q];

    float acc[4][8];
    #pragma unroll
    for (int i = 0; i < 4; ++i)
        #pragma unroll
        for (int j = 0; j < 8; ++j) acc[i][j] = 0.f;

    const float4* __restrict__ W14 = reinterpret_cast<const float4*>(W1);
    float4* w_s4 = reinterpret_cast<float4*>(w_s);

    for (int kc = 0; kc < 4; ++kc) {
        if (kc) __syncthreads();
        #pragma unroll
        for (int q = 0; q < 8; ++q)
            w_s4[t + 256 * q] = W14[kc * 2048 + t + 256 * q];
        __syncthreads();

        #pragma unroll
        for (int k4 = 0; k4 < 32; k4 += 4) {
            float4 a4[4];
            #pragma unroll
            for (int i = 0; i < 4; ++i)
                a4[i] = *reinterpret_cast<const float4*>(
                    &u_s[(rg + 8 * i) * 128 + kc * 32 + k4]);
            #pragma unroll
            for (int kk = 0; kk < 4; ++kk) {
                float b[8];
                #pragma unroll
                for (int j = 0; j < 8; ++j)
                    b[j] = w_s[(k4 + kk) * 256 + cg + 32 * j];
                #pragma unroll
                for (int i = 0; i < 4; ++i) {
                    float av = (kk == 0) ? a4[i].x : (kk == 1) ? a4[i].y
                             : (kk == 2) ? a4[i].z : a4[i].w;
                    #pragma unroll
                    for (int j = 0; j < 8; ++j)
                        acc[i][j] = fmaf(av, b[j], acc[i][j]);
                }
            }
        }
    }

    const float bias2 = b2[0];
    #pragma unroll
    for (int i = 0; i < 4; ++i) {
        float partial = 0.f;
        #pragma unroll
        for (int j = 0; j < 8; ++j) {
            int c = cg + 32 * j;
            float x = acc[i][j] + b1[c];
            float h = fmaxf(x, 0.f) + log1pf(expf(-fabsf(x))) - kSHIFT;
            partial += h * W2[c];
        }
        #pragma unroll
        for (int m = 16; m >= 1; m >>= 1)
            partial += __shfl_xor(partial, m);
        if (cg == 0)
            out[row0 + rg + 8 * i] = partial + bias2;
    }
}

extern "C" void kernel_launch(void* const* d_in, const int* in_sizes, int n_in,
                              void* d_out, int out_size, void* d_ws, size_t ws_size,
                              hipStream_t stream) {
    const float* v     = (const float*)d_in[0];
    const int*   batch = (const int*)d_in[1];
    const float* W1    = (const float*)d_in[2];
    const float* b1    = (const float*)d_in[3];
    const float* W2    = (const float*)d_in[4];
    const float* b2    = (const float*)d_in[5];
    float* out = (float*)d_out;

    const int n_nodes = in_sizes[0] / HIDDEN;   // 500000

    float* u   = (float*)d_ws;                                      // 8 MB
    int*   offs = (int*)((char*)d_ws + (size_t)NGRAPH * HIDDEN * 4); // 64 KB + 4

    const int n_waves = SEG_BLOCKS * 4;
    const int rows_per_wave = (n_nodes + n_waves - 1) / n_waves;    // 62

    offsets_kernel<<<(n_nodes + 255) / 256, 256, 0, stream>>>(
        batch, offs, (float4*)u, n_nodes);
    seg_sum_kernel<<<SEG_BLOCKS, 256, 0, stream>>>(
        v, batch, offs, u, n_nodes, rows_per_wave);
    mlp_kernel<<<MLP_BLOCKS, 256, 0, stream>>>(u, W1, b1, W2, b2, out);
}

// Round 6
// 77.960 us; speedup vs baseline: 1.3241x; 1.3241x over previous
//
#include <hip/hip_runtime.h>
#include <math.h>

#define HIDDEN 128
#define NGRAPH 16384
#define GPB 32                  // graphs per block
#define NBLK (NGRAPH / GPB)     // 512 blocks, 2 resident/CU

// shifted-softplus shift = log(2)
__device__ __constant__ float kSHIFT = 0.69314718055994530942f;

// ---------------------------------------------------------------------------
// Kernel 0: boundary scan. batch sorted; thread i writes offs[g]=i for every
// graph g starting at i (covers empty graphs). offs[NGRAPH]=n_nodes.
// ---------------------------------------------------------------------------
__global__ __launch_bounds__(256) void offsets_kernel(
    const int* __restrict__ batch, int* __restrict__ offs, int n_nodes)
{
    int i = blockIdx.x * blockDim.x + threadIdx.x;
    if (i >= n_nodes) return;
    int b = batch[i];
    int prev = (i == 0) ? -1 : batch[i - 1];
    for (int g = prev + 1; g <= b; ++g) offs[g] = i;        // rare
    if (i == n_nodes - 1)
        for (int g = b + 1; g <= NGRAPH; ++g) offs[g] = n_nodes;
}

// ---------------------------------------------------------------------------
// Fused kernel: 512 blocks x 256 threads, 32 graphs/block.
// Phase 1 (restructured): each wave streams the CONTIGUOUS row range of its
//   8 graphs in one pass. 64 lanes cover one 128-float row as float2
//   (8 B/lane, coalesced); rows loaded 8-at-a-time in a straight-line block
//   (8 loads in flight/lane), then accumulated with wave-uniform boundary
//   flushes into u_s (LDS). No pipeline drains at graph boundaries, no shfl,
//   no global atomics, u never touches HBM. Offsets live in LDS (offs_s).
// Phase 2: 32x256 MLP tile, acc[4][8] register blocking (unchanged from R3;
//   conflict-free LDS patterns). W1 chunk 0 prefetched during phase 1.
// LDS: 16 KB u_s + 32 KB w_s -> 2 blocks/CU.
// ---------------------------------------------------------------------------
__global__ __launch_bounds__(256, 2) void fused_kernel(
    const float* __restrict__ v, const int* __restrict__ offs,
    const float* __restrict__ W1, const float* __restrict__ b1,
    const float* __restrict__ W2, const float* __restrict__ b2,
    float* __restrict__ out)
{
    __shared__ float u_s[GPB * HIDDEN];   // 16 KB
    __shared__ float w_s[32 * 256];       // 32 KB
    __shared__ int   offs_s[GPB + 1];     // 33 ints

    const int t  = threadIdx.x;
    const int l  = t & 63;
    const int w  = t >> 6;                 // wave id 0..3
    const int g0 = blockIdx.x * GPB;

    if (t < GPB + 1) offs_s[t] = offs[g0 + t];
    __syncthreads();

    // prefetch W1 chunk 0 into w_s (one-time vmcnt stall, frees a phase-2 stage)
    const float4* __restrict__ W14 = reinterpret_cast<const float4*>(W1);
    float4* w_s4 = reinterpret_cast<float4*>(w_s);
    #pragma unroll
    for (int q = 0; q < 8; ++q)
        w_s4[t + 256 * q] = W14[t + 256 * q];

    // ---------------- Phase 1: continuous segment-sum stream ----------------
    const float2* __restrict__ v2 = reinterpret_cast<const float2*>(v);
    float2* u_s2 = reinterpret_cast<float2*>(u_s);

    const int w8 = w * 8;                  // this wave's first local graph
    const int lo = offs_s[w8];
    const int hi = offs_s[w8 + 8];
    int cur = 0;                           // local graph within the wave's 8
    int bnd = offs_s[w8 + 1];              // next boundary row
    float accx = 0.f, accy = 0.f;

    for (int r = lo; r < hi; r += 8) {
        // straight-line load block: 8 float2 loads in flight per lane
        float2 x[8];
        #pragma unroll
        for (int q = 0; q < 8; ++q) {
            int rq = r + q;
            rq = (rq < hi) ? rq : (hi - 1);          // clamp tail (uniform)
            x[q] = v2[(size_t)rq * 64 + l];
        }
        // accumulate with rare wave-uniform boundary flushes
        #pragma unroll
        for (int q = 0; q < 8; ++q) {
            if (r + q < hi) {
                while (r + q >= bnd) {               // taken ~1 in 30 rows
                    u_s2[(w8 + cur) * 64 + l] = make_float2(accx, accy);
                    accx = 0.f; accy = 0.f;
                    ++cur;
                    bnd = offs_s[w8 + cur + 1];      // max index w8+8 <= 32
                }
                accx += x[q].x; accy += x[q].y;
            }
        }
    }
    while (cur < 8) {                                 // flush last + empties
        u_s2[(w8 + cur) * 64 + l] = make_float2(accx, accy);
        accx = 0.f; accy = 0.f;
        ++cur;
    }
    __syncthreads();

    // ---------------- Phase 2: MLP on the 32-row tile ----------------
    const int cg = t & 31;   // cols cg + 32j
    const int rg = t >> 5;   // rows rg + 8i

    float acc[4][8];
    #pragma unroll
    for (int i = 0; i < 4; ++i)
        #pragma unroll
        for (int j = 0; j < 8; ++j) acc[i][j] = 0.f;

    for (int kc = 0; kc < 4; ++kc) {
        if (kc) {   // chunk 0 already staged during phase 1
            __syncthreads();
            #pragma unroll
            for (int q = 0; q < 8; ++q)
                w_s4[t + 256 * q] = W14[kc * 2048 + t + 256 * q];
            __syncthreads();
        }

        #pragma unroll
        for (int k4 = 0; k4 < 32; k4 += 4) {
            float4 a4[4];
            #pragma unroll
            for (int i = 0; i < 4; ++i)
                a4[i] = *reinterpret_cast<const float4*>(
                    &u_s[(rg + 8 * i) * 128 + kc * 32 + k4]);
            #pragma unroll
            for (int kk = 0; kk < 4; ++kk) {
                float b[8];
                #pragma unroll
                for (int j = 0; j < 8; ++j)
                    b[j] = w_s[(k4 + kk) * 256 + cg + 32 * j];
                #pragma unroll
                for (int i = 0; i < 4; ++i) {
                    float av = (kk == 0) ? a4[i].x : (kk == 1) ? a4[i].y
                             : (kk == 2) ? a4[i].z : a4[i].w;
                    #pragma unroll
                    for (int j = 0; j < 8; ++j)
                        acc[i][j] = fmaf(av, b[j], acc[i][j]);
                }
            }
        }
    }

    // epilogue: bias, shifted softplus, W2 contraction, 32-lane reduce
    const float bias2 = b2[0];
    #pragma unroll
    for (int i = 0; i < 4; ++i) {
        float partial = 0.f;
        #pragma unroll
        for (int j = 0; j < 8; ++j) {
            int c = cg + 32 * j;
            float x = acc[i][j] + b1[c];
            float h = fmaxf(x, 0.f) + log1pf(expf(-fabsf(x))) - kSHIFT;
            partial += h * W2[c];
        }
        #pragma unroll
        for (int m = 16; m >= 1; m >>= 1)
            partial += __shfl_xor(partial, m);
        if (cg == 0)
            out[g0 + rg + 8 * i] = partial + bias2;
    }
}

extern "C" void kernel_launch(void* const* d_in, const int* in_sizes, int n_in,
                              void* d_out, int out_size, void* d_ws, size_t ws_size,
                              hipStream_t stream) {
    const float* v     = (const float*)d_in[0];
    const int*   batch = (const int*)d_in[1];
    const float* W1    = (const float*)d_in[2];
    const float* b1    = (const float*)d_in[3];
    const float* W2    = (const float*)d_in[4];
    const float* b2    = (const float*)d_in[5];
    float* out = (float*)d_out;

    const int n_nodes = in_sizes[0] / HIDDEN;   // 500000
    int* offs = (int*)d_ws;                     // (NGRAPH+1) ints

    offsets_kernel<<<(n_nodes + 255) / 256, 256, 0, stream>>>(batch, offs, n_nodes);
    fused_kernel<<<NBLK, 256, 0, stream>>>(v, offs, W1, b1, W2, b2, out);
}

// Round 7
// 77.175 us; speedup vs baseline: 1.3376x; 1.0102x over previous
//
#include <hip/hip_runtime.h>
#include <math.h>

#define HIDDEN 128
#define NGRAPH 16384
#define GPB 32                  // graphs per block
#define NBLK (NGRAPH / GPB)     // 512 blocks, 2 resident/CU

// shifted-softplus shift = log(2)
__device__ __constant__ float kSHIFT = 0.69314718055994530942f;

// ---------------------------------------------------------------------------
// Kernel 0: boundary scan. batch sorted; thread i writes offs[g]=i for every
// graph g starting at i (covers empty graphs). offs[NGRAPH]=n_nodes.
// ---------------------------------------------------------------------------
__global__ __launch_bounds__(256) void offsets_kernel(
    const int* __restrict__ batch, int* __restrict__ offs, int n_nodes)
{
    int i = blockIdx.x * blockDim.x + threadIdx.x;
    if (i >= n_nodes) return;
    int b = batch[i];
    int prev = (i == 0) ? -1 : batch[i - 1];
    for (int g = prev + 1; g <= b; ++g) offs[g] = i;        // rare
    if (i == n_nodes - 1)
        for (int g = b + 1; g <= NGRAPH; ++g) offs[g] = n_nodes;
}

// ---------------------------------------------------------------------------
// Fused kernel: 512 blocks x 256 threads, 32 graphs/block.
// Phase 1 (unchanged from R6): each wave streams the contiguous row range of
//   its 8 graphs; 64 lanes cover a row as float2; rows loaded 8-at-a-time in
//   a straight-line block; wave-uniform boundary flushes into u_s.
// Phase 2 (CHANGED): thread's 8 columns are {cg*4+jj} and {128+cg*4+jj}
//   (jj=0..3) so b-loads are 2x ds_read_b128 per k (was 8x ds_read_b32).
//   Cuts phase-2 LDS issue ~4x; w_s layout/staging unchanged.
// LDS: 16 KB u_s + 32 KB w_s -> 2 blocks/CU.
// ---------------------------------------------------------------------------
__global__ __launch_bounds__(256, 2) void fused_kernel(
    const float* __restrict__ v, const int* __restrict__ offs,
    const float* __restrict__ W1, const float* __restrict__ b1,
    const float* __restrict__ W2, const float* __restrict__ b2,
    float* __restrict__ out)
{
    __shared__ float u_s[GPB * HIDDEN];   // 16 KB
    __shared__ float w_s[32 * 256];       // 32 KB
    __shared__ int   offs_s[GPB + 1];     // 33 ints

    const int t  = threadIdx.x;
    const int l  = t & 63;
    const int w  = t >> 6;                 // wave id 0..3
    const int g0 = blockIdx.x * GPB;

    if (t < GPB + 1) offs_s[t] = offs[g0 + t];
    __syncthreads();

    // prefetch W1 chunk 0 into w_s (frees one stage+sync from phase 2)
    const float4* __restrict__ W14 = reinterpret_cast<const float4*>(W1);
    float4* w_s4 = reinterpret_cast<float4*>(w_s);
    #pragma unroll
    for (int q = 0; q < 8; ++q)
        w_s4[t + 256 * q] = W14[t + 256 * q];

    // ---------------- Phase 1: continuous segment-sum stream ----------------
    const float2* __restrict__ v2 = reinterpret_cast<const float2*>(v);
    float2* u_s2 = reinterpret_cast<float2*>(u_s);

    const int w8 = w * 8;                  // this wave's first local graph
    const int lo = offs_s[w8];
    const int hi = offs_s[w8 + 8];
    int cur = 0;                           // local graph within the wave's 8
    int bnd = offs_s[w8 + 1];              // next boundary row
    float accx = 0.f, accy = 0.f;

    for (int r = lo; r < hi; r += 8) {
        // straight-line load block: 8 float2 loads in flight per lane
        float2 x[8];
        #pragma unroll
        for (int q = 0; q < 8; ++q) {
            int rq = r + q;
            rq = (rq < hi) ? rq : (hi - 1);          // clamp tail (uniform)
            x[q] = v2[(size_t)rq * 64 + l];
        }
        // accumulate with rare wave-uniform boundary flushes
        #pragma unroll
        for (int q = 0; q < 8; ++q) {
            if (r + q < hi) {
                while (r + q >= bnd) {               // taken ~1 in 30 rows
                    u_s2[(w8 + cur) * 64 + l] = make_float2(accx, accy);
                    accx = 0.f; accy = 0.f;
                    ++cur;
                    bnd = offs_s[w8 + cur + 1];      // max index w8+8 <= 32
                }
                accx += x[q].x; accy += x[q].y;
            }
        }
    }
    while (cur < 8) {                                 // flush last + empties
        u_s2[(w8 + cur) * 64 + l] = make_float2(accx, accy);
        accx = 0.f; accy = 0.f;
        ++cur;
    }
    __syncthreads();

    // ---------------- Phase 2: MLP on the 32-row tile ----------------
    // thread t: rows rg+8i (i=0..3), cols cg*4+jj and 128+cg*4+jj (jj=0..3)
    const int cg = t & 31;   // col-quad id
    const int rg = t >> 5;   // row group

    float acc[4][8];         // [i][jh*4+jj]
    #pragma unroll
    for (int i = 0; i < 4; ++i)
        #pragma unroll
        for (int j = 0; j < 8; ++j) acc[i][j] = 0.f;

    for (int kc = 0; kc < 4; ++kc) {
        if (kc) {   // chunk 0 already staged during phase 1
            __syncthreads();
            #pragma unroll
            for (int q = 0; q < 8; ++q)
                w_s4[t + 256 * q] = W14[kc * 2048 + t + 256 * q];
            __syncthreads();
        }

        #pragma unroll
        for (int k4 = 0; k4 < 32; k4 += 4) {
            float4 a4[4];
            #pragma unroll
            for (int i = 0; i < 4; ++i)
                a4[i] = *reinterpret_cast<const float4*>(
                    &u_s[(rg + 8 * i) * 128 + kc * 32 + k4]);
            #pragma unroll
            for (int kk = 0; kk < 4; ++kk) {
                const float4 b0 = *reinterpret_cast<const float4*>(
                    &w_s[(k4 + kk) * 256 + cg * 4]);
                const float4 b1q = *reinterpret_cast<const float4*>(
                    &w_s[(k4 + kk) * 256 + 128 + cg * 4]);
                #pragma unroll
                for (int i = 0; i < 4; ++i) {
                    const float av = (kk == 0) ? a4[i].x : (kk == 1) ? a4[i].y
                                   : (kk == 2) ? a4[i].z : a4[i].w;
                    acc[i][0] = fmaf(av, b0.x,  acc[i][0]);
                    acc[i][1] = fmaf(av, b0.y,  acc[i][1]);
                    acc[i][2] = fmaf(av, b0.z,  acc[i][2]);
                    acc[i][3] = fmaf(av, b0.w,  acc[i][3]);
                    acc[i][4] = fmaf(av, b1q.x, acc[i][4]);
                    acc[i][5] = fmaf(av, b1q.y, acc[i][5]);
                    acc[i][6] = fmaf(av, b1q.z, acc[i][6]);
                    acc[i][7] = fmaf(av, b1q.w, acc[i][7]);
                }
            }
        }
    }

    // epilogue: bias, shifted softplus, W2 contraction, 32-lane reduce
    const float bias2 = b2[0];
    #pragma unroll
    for (int i = 0; i < 4; ++i) {
        float partial = 0.f;
        #pragma unroll
        for (int jh = 0; jh < 2; ++jh)
            #pragma unroll
            for (int jj = 0; jj < 4; ++jj) {
                const int c = cg * 4 + jj + 128 * jh;
                float x = acc[i][jh * 4 + jj] + b1[c];
                float h = fmaxf(x, 0.f) + log1pf(expf(-fabsf(x))) - kSHIFT;
                partial += h * W2[c];
            }
        #pragma unroll
        for (int m = 16; m >= 1; m >>= 1)
            partial += __shfl_xor(partial, m);
        if (cg == 0)
            out[g0 + rg + 8 * i] = partial + bias2;
    }
}

extern "C" void kernel_launch(void* const* d_in, const int* in_sizes, int n_in,
                              void* d_out, int out_size, void* d_ws, size_t ws_size,
                              hipStream_t stream) {
    const float* v     = (const float*)d_in[0];
    const int*   batch = (const int*)d_in[1];
    const float* W1    = (const float*)d_in[2];
    const float* b1    = (const float*)d_in[3];
    const float* W2    = (const float*)d_in[4];
    const float* b2    = (const float*)d_in[5];
    float* out = (float*)d_out;

    const int n_nodes = in_sizes[0] / HIDDEN;   // 500000
    int* offs = (int*)d_ws;                     // (NGRAPH+1) ints

    offsets_kernel<<<(n_nodes + 255) / 256, 256, 0, stream>>>(batch, offs, n_nodes);
    fused_kernel<<<NBLK, 256, 0, stream>>>(v, offs, W1, b1, W2, b2, out);
}

// Round 8
// 60.274 us; speedup vs baseline: 1.7126x; 1.2804x over previous
//
#include <hip/hip_runtime.h>
#include <math.h>

#define HIDDEN 128
#define NGRAPH 16384
#define GPB 32                  // graphs per block
#define NBLK (NGRAPH / GPB)     // 512 blocks
#define NTHR 512                // 8 waves/block; 2 blocks/CU = 16 waves/CU

typedef __attribute__((ext_vector_type(8))) short short8;   // 8 bf16
typedef __attribute__((ext_vector_type(4))) float f32x4;    // MFMA accum

// shifted-softplus shift = log(2)
__device__ __constant__ float kSHIFT = 0.69314718055994530942f;

// fp32 -> bf16 (RNE), bit-level
__device__ __forceinline__ unsigned short f2bf(float f) {
    unsigned int u = __builtin_bit_cast(unsigned int, f);
    u = (u + 0x7FFFu + ((u >> 16) & 1u)) >> 16;
    return (unsigned short)u;
}

// ---------------------------------------------------------------------------
// Kernel 0: boundary scan. batch sorted; thread i writes offs[g]=i for every
// graph g starting at i (covers empty graphs). offs[NGRAPH]=n_nodes.
// ---------------------------------------------------------------------------
__global__ __launch_bounds__(256) void offsets_kernel(
    const int* __restrict__ batch, int* __restrict__ offs, int n_nodes)
{
    int i = blockIdx.x * blockDim.x + threadIdx.x;
    if (i >= n_nodes) return;
    int b = batch[i];
    int prev = (i == 0) ? -1 : batch[i - 1];
    for (int g = prev + 1; g <= b; ++g) offs[g] = i;        // rare
    if (i == n_nodes - 1)
        for (int g = b + 1; g <= NGRAPH; ++g) offs[g] = n_nodes;
}

// ---------------------------------------------------------------------------
// Fused kernel: 512 blocks x 512 threads (8 waves), 32 graphs/block.
// - B-frags: each wave owns a 32-col stripe of W1; fragments loaded ONCE from
//   global into registers as bf16 (8 frags = 32 VGPR). No W LDS at all.
// - Phase 1 (same streaming as R6/R7, 4 graphs/wave): rows loaded 8-at-a-time
//   straight-line (8 float2 loads in flight/lane), wave-uniform boundary
//   flushes convert the row to bf16 and write it XOR-swizzled into u_b LDS.
// - Phase 2: 16 x v_mfma_f32_16x16x32_bf16 per wave. A-frags via conflict-free
//   swizzled ds_read_b128 from u_b. Epilogue: bias -> shifted softplus ->
//   *W2 -> 16-lane shfl reduce -> cross-wave LDS reduce -> out.
// LDS: 8 KB u_b + 1 KB red + offs = ~9.2 KB. launch_bounds(512,4) -> VGPR<=128.
// ---------------------------------------------------------------------------
__global__ __launch_bounds__(NTHR, 4) void fused_kernel(
    const float* __restrict__ v, const int* __restrict__ offs,
    const float* __restrict__ W1, const float* __restrict__ b1,
    const float* __restrict__ W2, const float* __restrict__ b2,
    float* __restrict__ out)
{
    __shared__ short u_b[GPB * HIDDEN];    // 8 KB, bf16, k XOR-swizzled per row
    __shared__ float red_s[8][GPB];        // 1 KB
    __shared__ int   offs_s[GPB + 1];

    const int t  = threadIdx.x;
    const int l  = t & 63;
    const int w  = t >> 6;                 // wave id 0..7
    const int g0 = blockIdx.x * GPB;

    if (t < GPB + 1) offs_s[t] = offs[g0 + t];

    // ---- B-fragments: W1 cols [w*32, w*32+32), bf16, registers ----
    // frag[ct][kt]: lane l holds B[k = kt*32+(l>>4)*8+j][col = w*32+ct*16+(l&15)]
    short8 bfrag[2][4];
    {
        const int lcol = w * 32 + (l & 15);
        #pragma unroll
        for (int ct = 0; ct < 2; ++ct) {
            const int col = lcol + ct * 16;
            #pragma unroll
            for (int kt = 0; kt < 4; ++kt) {
                const int k0 = kt * 32 + (l >> 4) * 8;
                short8 f;
                #pragma unroll
                for (int j = 0; j < 8; ++j)
                    f[j] = (short)f2bf(W1[(size_t)(k0 + j) * 256 + col]);
                bfrag[ct][kt] = f;
            }
        }
    }
    __syncthreads();   // offs_s ready

    // ---------------- Phase 1: continuous segment-sum stream ----------------
    const float2* __restrict__ v2 = reinterpret_cast<const float2*>(v);
    const int w4 = w * 4;                  // this wave's first local graph
    const int lo = offs_s[w4];
    const int hi = offs_s[w4 + 4];
    int cur = 0;
    int bnd = offs_s[w4 + 1];
    float accx = 0.f, accy = 0.f;
    const int k2 = 2 * l;                  // lane's k-pair base

    for (int r = lo; r < hi; r += 8) {
        float2 x[8];
        #pragma unroll
        for (int q = 0; q < 8; ++q) {
            int rq = r + q;
            rq = (rq < hi) ? rq : (hi - 1);          // clamp tail (uniform)
            x[q] = v2[(size_t)rq * 64 + l];
        }
        #pragma unroll
        for (int q = 0; q < 8; ++q) {
            if (r + q < hi) {
                while (r + q >= bnd) {               // taken ~1 in 30 rows
                    const int row = w4 + cur;
                    const int idx = row * HIDDEN + (k2 ^ ((row & 7) * 8));
                    unsigned int pk = (unsigned int)f2bf(accx)
                                    | ((unsigned int)f2bf(accy) << 16);
                    *reinterpret_cast<unsigned int*>(&u_b[idx]) = pk;
                    accx = 0.f; accy = 0.f;
                    ++cur;
                    bnd = offs_s[w4 + cur + 1];      // max idx w4+4 <= 32
                }
                accx += x[q].x; accy += x[q].y;
            }
        }
    }
    while (cur < 4) {                                 // flush last + empties
        const int row = w4 + cur;
        const int idx = row * HIDDEN + (k2 ^ ((row & 7) * 8));
        unsigned int pk = (unsigned int)f2bf(accx)
                        | ((unsigned int)f2bf(accy) << 16);
        *reinterpret_cast<unsigned int*>(&u_b[idx]) = pk;
        accx = 0.f; accy = 0.f;
        ++cur;
    }
    __syncthreads();

    // ---------------- Phase 2: MFMA MLP ----------------
    f32x4 acc[2][2];                       // [row-tile][col-tile]
    #pragma unroll
    for (int rt = 0; rt < 2; ++rt)
        #pragma unroll
        for (int ct = 0; ct < 2; ++ct)
            acc[rt][ct] = (f32x4){0.f, 0.f, 0.f, 0.f};

    #pragma unroll
    for (int kt = 0; kt < 4; ++kt) {
        #pragma unroll
        for (int rt = 0; rt < 2; ++rt) {
            const int row = rt * 16 + (l & 15);
            const int k0  = kt * 32 + (l >> 4) * 8;
            short8 a = *reinterpret_cast<const short8*>(
                &u_b[row * HIDDEN + (k0 ^ ((row & 7) * 8))]);
            #pragma unroll
            for (int ct = 0; ct < 2; ++ct)
                acc[rt][ct] = __builtin_amdgcn_mfma_f32_16x16x32_bf16(
                    a, bfrag[ct][kt], acc[rt][ct], 0, 0, 0);
        }
    }

    // epilogue: bias -> shifted softplus -> *W2 -> reduce 16 cols -> LDS
    float b1c[2], w2c[2];
    #pragma unroll
    for (int ct = 0; ct < 2; ++ct) {
        const int col = w * 32 + ct * 16 + (l & 15);
        b1c[ct] = b1[col];
        w2c[ct] = W2[col];
    }
    #pragma unroll
    for (int rt = 0; rt < 2; ++rt) {
        float p[4] = {0.f, 0.f, 0.f, 0.f};
        #pragma unroll
        for (int ct = 0; ct < 2; ++ct)
            #pragma unroll
            for (int reg = 0; reg < 4; ++reg) {
                float x = acc[rt][ct][reg] + b1c[ct];
                float h = fmaxf(x, 0.f) + log1pf(expf(-fabsf(x))) - kSHIFT;
                p[reg] = fmaf(h, w2c[ct], p[reg]);
            }
        #pragma unroll
        for (int reg = 0; reg < 4; ++reg) {
            float s = p[reg];
            s += __shfl_xor(s, 1);
            s += __shfl_xor(s, 2);
            s += __shfl_xor(s, 4);
            s += __shfl_xor(s, 8);
            if ((l & 15) == 0)
                red_s[w][rt * 16 + (l >> 4) * 4 + reg] = s;
        }
    }
    __syncthreads();

    if (t < GPB) {
        float s = (red_s[0][t] + red_s[1][t]) + (red_s[2][t] + red_s[3][t])
                + (red_s[4][t] + red_s[5][t]) + (red_s[6][t] + red_s[7][t]);
        out[g0 + t] = s + b2[0];
    }
}

extern "C" void kernel_launch(void* const* d_in, const int* in_sizes, int n_in,
                              void* d_out, int out_size, void* d_ws, size_t ws_size,
                              hipStream_t stream) {
    const float* v     = (const float*)d_in[0];
    const int*   batch = (const int*)d_in[1];
    const float* W1    = (const float*)d_in[2];
    const float* b1    = (const float*)d_in[3];
    const float* W2    = (const float*)d_in[4];
    const float* b2    = (const float*)d_in[5];
    float* out = (float*)d_out;

    const int n_nodes = in_sizes[0] / HIDDEN;   // 500000
    int* offs = (int*)d_ws;                     // (NGRAPH+1) ints

    offsets_kernel<<<(n_nodes + 255) / 256, 256, 0, stream>>>(batch, offs, n_nodes);
    fused_kernel<<<NBLK, NTHR, 0, stream>>>(v, offs, W1, b1, W2, b2, out);
}